// Round 6
// baseline (245.283 us; speedup 1.0000x reference)
//
#include <hip/hip_runtime.h>
#include <hip/hip_bf16.h>

// Reference collapses: softmax over singleton axis==1 -> attention weights == 1,
// so ctx[b,h] = sum_l fmap[b,l,h], out[b,t,c] = dot(ctx[b,:], W_gen[c,:]) + b_gen[c]
// broadcast over all t. LSTM / embedding / text are dead code.
//
// R6: single-dispatch fusion with fine-grained producer/consumer sync.
// Block n (cx=n&127, by=n>>7): produce 16 ctx rows -> agent-release arrive at
// flag[by] -> spin till 128 arrivals -> acquire -> R5's GEMM+bcast body.
// cx-minor id keeps same-cx blocks on one XCD (W slice L2-pinned, as R5).
// Every block produces before waiting + full co-residency => deadlock-free.

constexpr int Hd = 512;   // hidden (K)
constexpr int Cd = 4096;  // classes (N)
constexpr int Bd = 64;    // batch (M)
constexpr int Td = 32;    // timesteps (broadcast)
constexpr int Ld = 256;   // FH*FW
constexpr int CG = 32;    // c per block
constexpr int GX = Cd / CG;       // 128 c-groups
constexpr int GY = Bd / 4;        // 16 b-groups
constexpr int NB = GX * GY;       // 2048 blocks
constexpr int CTX_FLOATS = Bd * Hd;

// all-DPP 16-lane rotate-add; 0x121:ror1 0x122:ror2 0x124:ror4 0x128:ror8
template<int CTRL>
__device__ __forceinline__ float ror_add(float v) {
    int r = __builtin_amdgcn_update_dpp(0, __float_as_int(v), CTRL, 0xF, 0xF, false);
    return v + __int_as_float(r);
}

__global__ __launch_bounds__(256, 8) void fused2(const float* __restrict__ fmap,
                                                 const float* __restrict__ Wgen,
                                                 const float* __restrict__ bgen,
                                                 float* __restrict__ out,
                                                 float* ctx, int* flag) {
    __shared__ float part[4 * CG * 4];  // [wave][c_local][b_local]
    const int tid  = threadIdx.x;
    const int w    = tid >> 6;
    const int lane = tid & 63;
    const int n    = blockIdx.x;
    const int cx   = n & (GX - 1);
    const int by   = n >> 7;

    // ---------- phase 1: produce 16 ctx rows (4 rows per wave) ----------
    {
        const int R0 = by * 2048 + cx * 16 + w * 4;
        const float4* in4 = reinterpret_cast<const float4*>(fmap);
        float4 v[4];
        #pragma unroll
        for (int r = 0; r < 4; ++r)
            v[r] = in4[(size_t)(R0 + r) * 64 + lane];
        float s[4];
        #pragma unroll
        for (int r = 0; r < 4; ++r) {
            float a = v[r].x + v[r].y + v[r].z + v[r].w;
            a += __shfl_xor(a, 16, 64);
            a += __shfl_xor(a, 32, 64);
            a = ror_add<0x121>(a);
            a = ror_add<0x122>(a);
            a = ror_add<0x124>(a);
            a = ror_add<0x128>(a);   // full 64-lane sum in every lane
            s[r] = a;
        }
        if (lane < 4) {
            float val = s[0];
            #pragma unroll
            for (int r = 1; r < 4; ++r) val = (lane == r) ? s[r] : val;
            ctx[R0 + lane] = val;
        }
    }
    __syncthreads();   // drains all waves' ctx stores out of the CU (vmcnt(0))
    if (tid == 0)
        __hip_atomic_fetch_add(flag + by, 1, __ATOMIC_RELEASE,
                               __HIP_MEMORY_SCOPE_AGENT);

    // ---------- wait for this b-group's 128 producers ----------
    if (tid == 0) {
        int it = 0;
        while (__hip_atomic_load(flag + by, __ATOMIC_RELAXED,
                                 __HIP_MEMORY_SCOPE_AGENT) < GX) {
            __builtin_amdgcn_s_sleep(4);
            if (++it > (1 << 24)) break;   // safety valve: no hang
        }
    }
    __syncthreads();
    (void)__hip_atomic_load(flag + by, __ATOMIC_ACQUIRE,
                            __HIP_MEMORY_SCOPE_AGENT);  // per-wave cache acquire

    // ---------- phase 2: out[b][t][c] = ctx[b,:]·W[c,:] + bias, bcast t ----------
    const int cpart = lane >> 4;
    const int hp    = lane & 15;
    const int cblk  = cx * CG;
    const int b0    = by * 4;

    const float4* W4 = reinterpret_cast<const float4*>(Wgen);
    const float4* X4 = reinterpret_cast<const float4*>(ctx);

    float4 xr[4][2];
    #pragma unroll
    for (int bb = 0; bb < 4; ++bb)
        #pragma unroll
        for (int j = 0; j < 2; ++j)
            xr[bb][j] = X4[(size_t)(b0 + bb) * 128 + w * 32 + j * 16 + hp];

    #pragma unroll 4
    for (int q = 0; q < CG / 4; ++q) {
        const int c = cblk + q * 4 + cpart;
        const size_t base = (size_t)c * 128 + w * 32 + hp;
        const float4 w0 = W4[base];
        const float4 w1 = W4[base + 16];
        float acc[4];
        #pragma unroll
        for (int bb = 0; bb < 4; ++bb) {
            float a = w0.x * xr[bb][0].x + w0.y * xr[bb][0].y
                    + w0.z * xr[bb][0].z + w0.w * xr[bb][0].w
                    + w1.x * xr[bb][1].x + w1.y * xr[bb][1].y
                    + w1.z * xr[bb][1].z + w1.w * xr[bb][1].w;
            a = ror_add<0x128>(a);
            a = ror_add<0x124>(a);
            a = ror_add<0x122>(a);
            a = ror_add<0x121>(a);      // full 16-lane sum in every lane
            acc[bb] = a;
        }
        if (hp == 0) {
            reinterpret_cast<float4*>(part)[w * CG + (q * 4 + cpart)] =
                make_float4(acc[0], acc[1], acc[2], acc[3]);
        }
    }
    __syncthreads();

    {
        const int cq = tid & 7;
        const int bl = (tid >> 3) & 3;
        const int tt = tid >> 5;
        float v[4];
        #pragma unroll
        for (int j = 0; j < 4; ++j) {
            const int cl = cq * 4 + j;
            v[j] = part[(0 * CG + cl) * 4 + bl] + part[(1 * CG + cl) * 4 + bl]
                 + part[(2 * CG + cl) * 4 + bl] + part[(3 * CG + cl) * 4 + bl]
                 + bgen[cblk + cl];
        }
        const float4 vv = make_float4(v[0], v[1], v[2], v[3]);
        float* o = out + (size_t)(b0 + bl) * Td * Cd + cblk + cq * 4;
        #pragma unroll
        for (int k = 0; k < 4; ++k) {
            const int t = tt + k * 8;
            *reinterpret_cast<float4*>(o + (size_t)t * Cd) = vv;
        }
    }
}

extern "C" void kernel_launch(void* const* d_in, const int* in_sizes, int n_in,
                              void* d_out, int out_size, void* d_ws, size_t ws_size,
                              hipStream_t stream) {
    const float* fmap = (const float*)d_in[0];   // [64,512,8,32]
    const float* Wgen = (const float*)d_in[9];   // [4096,512]
    const float* bgen = (const float*)d_in[10];  // [4096]
    float* out = (float*)d_out;                  // [64,32,4096]
    float* ctx = (float*)d_ws;                   // [64,512]
    int*   flag = (int*)((char*)d_ws + CTX_FLOATS * sizeof(float));

    hipMemsetAsync(flag, 0, GY * sizeof(int), stream);   // poison-safe flag reset
    fused2<<<dim3(NB), dim3(256), 0, stream>>>(fmap, Wgen, bgen, out, ctx, flag);
}

// Round 7
// 29.750 us; speedup vs baseline: 8.2449x; 8.2449x over previous
//
#include <hip/hip_runtime.h>
#include <hip/hip_bf16.h>

// Reference collapses: softmax over singleton axis==1 -> attention weights == 1,
// so ctx[b,h] = sum_l fmap[b,l,h], out[b,t,c] = dot(ctx[b,:], W_gen[c,:]) + b_gen[c]
// broadcast over all t. LSTM / embedding / text are dead code.
//
// R6 post-mortem: producer/consumer fusion hit the agent-scope release/acquire
// = per-XCD L2 writeback/invalidate storm (245us, VALU 3.3%). Fusion rejected.
// R7: two kernels; K2 widened to 128-c blocks so each (b,t) store chunk is
// 512B contiguous (was 128B) -> better DRAM page locality; 512 fat blocks.

constexpr int Hd = 512;   // hidden (K)
constexpr int Cd = 4096;  // classes (N)
constexpr int Bd = 64;    // batch (M)
constexpr int Td = 32;    // timesteps (broadcast)
constexpr int Ld = 256;   // FH*FW
constexpr int CG = 128;   // c per block in K2

// all-DPP 16-lane rotate-add; 0x121:ror1 0x122:ror2 0x124:ror4 0x128:ror8
template<int CTRL>
__device__ __forceinline__ float ror_add(float v) {
    int r = __builtin_amdgcn_update_dpp(0, __float_as_int(v), CTRL, 0xF, 0xF, false);
    return v + __int_as_float(r);
}

// ---------------- K1: ctx[row] = sum of 256 contiguous floats ----------------
// grid 1024 x 256thr; wave = 8 rows, loads all issued up front.
__global__ __launch_bounds__(256) void reduce_rows(const float* __restrict__ in,
                                                   float* __restrict__ ctx) {
    const int lane = threadIdx.x & 63;
    const int gw   = blockIdx.x * 4 + (threadIdx.x >> 6);  // global wave 0..4095
    const int row0 = gw * 8;
    const float4* in4 = reinterpret_cast<const float4*>(in);

    float4 v[8];
    #pragma unroll
    for (int r = 0; r < 8; ++r)
        v[r] = in4[(size_t)(row0 + r) * 64 + lane];   // 8 independent loads

    float s[8];
    #pragma unroll
    for (int r = 0; r < 8; ++r) {
        float a = v[r].x + v[r].y + v[r].z + v[r].w;
        a += __shfl_xor(a, 16, 64);
        a += __shfl_xor(a, 32, 64);
        a = ror_add<0x121>(a);
        a = ror_add<0x122>(a);
        a = ror_add<0x124>(a);
        a = ror_add<0x128>(a);   // full 64-lane sum in every lane
        s[r] = a;
    }
    if (lane < 8) {
        float val = s[0];
        #pragma unroll
        for (int r = 1; r < 8; ++r) val = (lane == r) ? s[r] : val;
        ctx[row0 + lane] = val;   // 32B contiguous store
    }
}

// ---------------- K2: out[b][t][c] = ctx[b,:]·W[c,:] + bias, bcast over t -------
// grid (Cd/CG=32, Bd/4=16) = 512 blocks, 256 thr (4 waves).
// wave w owns K-slice h in [w*128, w*128+128); lane = cpart*16 + hp.
// Same-cx blocks stride 32 in linear id (== 0 mod 8) -> same XCD -> W slice
// (256KB; 1MB/XCD) L2-resident across its 16 b-replicas.
// Stores: each (b,t) gets a 512B contiguous chunk (half-wave), 2 chunks/instr.
__global__ __launch_bounds__(256, 2) void gemm_bcast(const float* __restrict__ ctx,
                                                     const float* __restrict__ Wgen,
                                                     const float* __restrict__ bgen,
                                                     float* __restrict__ out) {
    __shared__ float4 part[4][CG];        // [wave][c_local] -> float4 over 4 b   (8KB)
    __shared__ float4 final4[4 * CG / 4]; // final[b][c-quad]                     (2KB)
    const int tid   = threadIdx.x;
    const int w     = tid >> 6;
    const int lane  = tid & 63;
    const int cpart = lane >> 4;
    const int hp    = lane & 15;
    const int cblk  = blockIdx.x * CG;
    const int b0    = blockIdx.y * 4;

    const float4* W4 = reinterpret_cast<const float4*>(Wgen);
    const float4* X4 = reinterpret_cast<const float4*>(ctx);

    // ctx registers: xr[bb][j] = ctx[b0+bb][w*128 + j*64 + hp*4 .. +3]
    float4 xr[4][2];
    #pragma unroll
    for (int bb = 0; bb < 4; ++bb)
        #pragma unroll
        for (int j = 0; j < 2; ++j)
            xr[bb][j] = X4[(size_t)(b0 + bb) * 128 + w * 32 + j * 16 + hp];

    #pragma unroll 8
    for (int q = 0; q < CG / 4; ++q) {    // 32 c-quads
        const int c = cblk + q * 4 + cpart;
        const size_t base = (size_t)c * 128 + w * 32 + hp;
        const float4 w0 = W4[base];        // h = w*128 + hp*4
        const float4 w1 = W4[base + 16];   // h = w*128 + 64 + hp*4
        float acc[4];
        #pragma unroll
        for (int bb = 0; bb < 4; ++bb) {
            float a = w0.x * xr[bb][0].x + w0.y * xr[bb][0].y
                    + w0.z * xr[bb][0].z + w0.w * xr[bb][0].w
                    + w1.x * xr[bb][1].x + w1.y * xr[bb][1].y
                    + w1.z * xr[bb][1].z + w1.w * xr[bb][1].w;
            a = ror_add<0x128>(a);
            a = ror_add<0x124>(a);
            a = ror_add<0x122>(a);
            a = ror_add<0x121>(a);      // full 16-lane sum in every lane
            acc[bb] = a;
        }
        if (hp == 0)
            part[w][q * 4 + cpart] = make_float4(acc[0], acc[1], acc[2], acc[3]);
    }
    __syncthreads();

    // combine 4 wave-partials + bias; transpose to final[b][c] in LDS
    if (tid < CG) {
        const float4 p0 = part[0][tid], p1 = part[1][tid],
                     p2 = part[2][tid], p3 = part[3][tid];
        const float bg = bgen[cblk + tid];
        float* ff = reinterpret_cast<float*>(final4);
        ff[0 * CG + tid] = p0.x + p1.x + p2.x + p3.x + bg;
        ff[1 * CG + tid] = p0.y + p1.y + p2.y + p3.y + bg;
        ff[2 * CG + tid] = p0.z + p1.z + p2.z + p3.z + bg;
        ff[3 * CG + tid] = p0.w + p1.w + p2.w + p3.w + bg;
    }
    __syncthreads();

    // stores: 128 chunks (4 b x 32 t), each 512B contiguous; half-wave per chunk
    const int hw  = tid >> 5;   // 0..7
    const int l32 = tid & 31;
    #pragma unroll
    for (int k = 0; k < 16; ++k) {
        const int ch = k * 8 + hw;        // 0..127
        const int bl = ch >> 5;
        const int tt = ch & 31;
        const float4 val = final4[bl * (CG / 4) + l32];
        float* o = out + (size_t)(b0 + bl) * Td * Cd + (size_t)tt * Cd
                       + cblk + l32 * 4;
        *reinterpret_cast<float4*>(o) = val;
    }
}

extern "C" void kernel_launch(void* const* d_in, const int* in_sizes, int n_in,
                              void* d_out, int out_size, void* d_ws, size_t ws_size,
                              hipStream_t stream) {
    const float* fmap = (const float*)d_in[0];   // [64,512,8,32]
    const float* Wgen = (const float*)d_in[9];   // [4096,512]
    const float* bgen = (const float*)d_in[10];  // [4096]
    float* out = (float*)d_out;                  // [64,32,4096]
    float* ctx = (float*)d_ws;                   // [64,512] scratch

    reduce_rows<<<dim3((Bd * Hd) / (4 * 8)), dim3(256), 0, stream>>>(fmap, ctx);
    gemm_bcast<<<dim3(Cd / CG, Bd / 4), dim3(256), 0, stream>>>(ctx, Wgen, bgen, out);
}